// Round 7
// baseline (234.878 us; speedup 1.0000x reference)
//
#include <hip/hip_runtime.h>
#include <hip/hip_bf16.h>

// GPT2 attention: hidden[2,2048,1024] -> qkv gemm -> causal MFMA flash attn
// (single-tile split-K chunks + merge) -> proj
// ws layout (48 MB):
//   hA     bf16 8 MB @ 0      (gemm_qkv A input; dead after -> attn partial
//                              overflow region P1, 4 MB used)
//   wqkvT  bf16 6 MB @ 8 MB   (dead after gemm_qkv -> lp partials, 655 KB)
//   wprojT bf16 2 MB @ 14 MB
//   qkv    bf16 24 MB @ 16 MB (Q scaled by log2(e)/8)
//   vA     bf16 8 MB @ 40 MB  (V in PV-frag layout from gemm epilogue; dead
//                              after attn -> merge writes aout here)
// d_out (16 MB): attn partial region P0 (slots 0..2047), later proj output.
//
// qkv GEMM: 8-phase 256x256 schedule (m201 template), BK=64, 8 waves,
// counted vmcnt(4) at phases 4/8, T2 XOR swizzle via pre-swizzled source.
// proj GEMM: triple-buffered 2-phase structure.
// Attention v6: BARRIER-FREE. K fragments read direct from global per wave
// (K tile is L2-resident; LDS staging only existed to share frags across
// waves, and its __syncthreads lockstep correlated all stalls -- per-SIMD
// MFMA busy was ~5% with ~4000-cyc tile latency). No LDS, no syncthreads:
// waves fully independent, counted vmcnt waits per MFMA, occupancy
// VGPR-capped only. V direct-from-global as before. Heavy-first LPT grid.

typedef __attribute__((ext_vector_type(4))) float  float4v;
typedef __attribute__((ext_vector_type(8))) short  short8v;
typedef __attribute__((ext_vector_type(4))) short  short4v;

#define ATT_SCALE 0.18033688011112042f   // log2(e) / sqrt(64)

__device__ __forceinline__ short f2bf(float f) {
  union { float f; unsigned u; } v; v.f = f;
  unsigned r = v.u + 0x7fffu + ((v.u >> 16) & 1u);   // RNE
  return (short)(r >> 16);
}
__device__ __forceinline__ float bf2f(short s) {
  union { unsigned u; float f; } v; v.u = ((unsigned)(unsigned short)s) << 16;
  return v.f;
}

// pack 4 floats -> 4 bf16 (round-half-up) via v_perm_b32
__device__ __forceinline__ short4v pack_bf16x4(float a, float b, float c, float d) {
  unsigned x0 = __builtin_bit_cast(unsigned, a) + 0x8000u;
  unsigned x1 = __builtin_bit_cast(unsigned, b) + 0x8000u;
  unsigned x2 = __builtin_bit_cast(unsigned, c) + 0x8000u;
  unsigned x3 = __builtin_bit_cast(unsigned, d) + 0x8000u;
  union { unsigned u[2]; short4v s; } r;
  r.u[0] = __builtin_amdgcn_perm(x1, x0, 0x07060302);
  r.u[1] = __builtin_amdgcn_perm(x3, x2, 0x07060302);
  return r.s;
}

// pack 4 floats -> 4 bf16 (RNE) via v_cvt_pk_bf16_f32
__device__ __forceinline__ short4v cvt_pk_bf16x4(float a, float b, float c, float d) {
  union { unsigned u[2]; short4v s; } r;
  asm("v_cvt_pk_bf16_f32 %0, %1, %2" : "=v"(r.u[0]) : "v"(a), "v"(b));
  asm("v_cvt_pk_bf16_f32 %0, %1, %2" : "=v"(r.u[1]) : "v"(c), "v"(d));
  return r.s;
}

// async global->LDS, 16B per lane; LDS dest = wave-uniform base + lane*16
__device__ __forceinline__ void gl_lds16(const void* g, void* l) {
  __builtin_amdgcn_global_load_lds(
      (const __attribute__((address_space(1))) unsigned*)g,
      (__attribute__((address_space(3))) unsigned*)l, 16, 0, 0);
}

// ---------------- merged prep: hidden->bf16, both weight transposes ----------
__global__ __launch_bounds__(256) void prep_kernel(
    const float* __restrict__ hidden, const float* __restrict__ w_attn,
    const float* __restrict__ w_proj, short* __restrict__ hA,
    short* __restrict__ wqkvT, short* __restrict__ wprojT) {
  __shared__ float tile[32][33];
  const int bx = blockIdx.x, t = threadIdx.x;
  if (bx < 4096) {                     // hidden [4096,1024] fp32 -> bf16
    const size_t i = ((size_t)bx * 256 + t) * 4;
    float4v v = *(const float4v*)(hidden + i);
    short4v o;
    #pragma unroll
    for (int k = 0; k < 4; k++) o[k] = f2bf(v[k]);
    *(short4v*)(hA + i) = o;
    return;
  }
  const float* in; short* out; int R, C, cx, cy;
  if (bx < 4096 + 3072) {              // w_attn [1024,3072] -> [3072,1024]
    in = w_attn; out = wqkvT; R = 1024; C = 3072;
    cx = (bx - 4096) % 96; cy = (bx - 4096) / 96;
  } else {                             // w_proj [1024,1024] -> [1024,1024]
    in = w_proj; out = wprojT; R = 1024; C = 1024;
    cx = (bx - 7168) % 32; cy = (bx - 7168) / 32;
  }
  const int tx = t & 31, ty = t >> 5;  // 32 x 8
  const int c0 = cx * 32, r0 = cy * 32;
  #pragma unroll
  for (int i = 0; i < 4; i++)
    tile[ty + i * 8][tx] = in[(size_t)(r0 + ty + i * 8) * C + c0 + tx];
  __syncthreads();
  #pragma unroll
  for (int i = 0; i < 4; i++) {
    const int cc = ty + i * 8;
    out[(size_t)(c0 + cc) * R + r0 + tx] = f2bf(tile[tx][cc]);
  }
}

// ---------------- qkv GEMM: 8-phase 256x256, BK=64, 8 waves ----------------
__global__ __launch_bounds__(512, 2) void gemm_qkv256(
    const short* __restrict__ A, const short* __restrict__ Bt,
    const float* __restrict__ bias, short* __restrict__ qkv,
    short* __restrict__ vA)
{
  __shared__ short As[2][256][64];   // 64 KB
  __shared__ short Bs[2][256][64];   // 64 KB
  const int K = 1024;
  const int t = threadIdx.x;
  const int lane = t & 63, w = t >> 6;          // 8 waves
  const int wm2 = w >> 2, wn4 = w & 3;          // 2M x 4N wave grid
  const int l16 = lane & 15, quad = lane >> 4;
  const int e7 = l16 & 7;                       // read-side swizzle key
  const int row0 = blockIdx.y * 256;
  const int col0 = blockIdx.x * 256;

  float4v acc[8][4] = {};

  const int srow = w * 8 + (lane >> 3);
  const int slog = (lane & 7) ^ (lane >> 3);
  const short* gA = A + (size_t)(row0 + srow) * K + slog * 8;
  const short* gB = Bt + (size_t)(col0 + srow) * K + slog * 8;
  const int sdst = (lane & 7) * 8;              // within-row shorts

  auto stageA = [&](int b, int qd, int kt) {
    gl_lds16(gA + (size_t)qd * 64 * K + kt * 64,
             &As[b][qd * 64 + w * 8 + (lane >> 3)][sdst]);
  };
  auto stageB = [&](int b, int qd, int kt) {
    gl_lds16(gB + (size_t)qd * 64 * K + kt * 64,
             &Bs[b][qd * 64 + w * 8 + (lane >> 3)][sdst]);
  };

  short8v af[4], bf0[4], bf1[4];
  auto ldA = [&](int b, int mh, int ks) {
    #pragma unroll
    for (int m = 0; m < 4; m++) {
      const int row = wm2 * 128 + mh * 64 + m * 16 + l16;
      af[m] = *(const short8v*)&As[b][row][((ks * 4 + quad) ^ e7) * 8];
    }
  };
  auto ldB = [&](short8v* bf, int b, int ks) {
    #pragma unroll
    for (int n = 0; n < 4; n++) {
      const int row = wn4 * 64 + n * 16 + l16;
      bf[n] = *(const short8v*)&Bs[b][row][((ks * 4 + quad) ^ e7) * 8];
    }
  };
  auto mm = [&](int mb, short8v* bf) {
    __builtin_amdgcn_s_setprio(1);
    #pragma unroll
    for (int m = 0; m < 4; m++)
      #pragma unroll
      for (int n = 0; n < 4; n++)
        acc[mb + m][n] =
            __builtin_amdgcn_mfma_f32_16x16x32_bf16(af[m], bf[n], acc[mb + m][n], 0, 0, 0);
    __builtin_amdgcn_s_setprio(0);
  };
  auto sync_mfma = [&]() {           // barrier -> lgkm drain (rule #18 fence)
    __builtin_amdgcn_sched_barrier(0);
    __builtin_amdgcn_s_barrier();
    asm volatile("s_waitcnt lgkmcnt(0)" ::: "memory");
    __builtin_amdgcn_sched_barrier(0);
  };
  auto endp = [&]() {                // trailing phase barrier
    __builtin_amdgcn_sched_barrier(0);
    __builtin_amdgcn_s_barrier();
    __builtin_amdgcn_sched_barrier(0);
  };

  // prologue: tile 0 (A+B, 8 quarters) + tile 1 B (4 quarters)
  #pragma unroll
  for (int qd = 0; qd < 4; qd++) stageA(0, qd, 0);
  #pragma unroll
  for (int qd = 0; qd < 4; qd++) stageB(0, qd, 0);
  #pragma unroll
  for (int qd = 0; qd < 4; qd++) stageB(1, qd, 1);
  asm volatile("s_waitcnt vmcnt(4)" ::: "memory");   // tile 0 landed
  __builtin_amdgcn_s_barrier();
  __builtin_amdgcn_sched_barrier(0);

  const int NIT = K / 128;           // 8 iterations, 2 K-tiles each
  #pragma unroll 1
  for (int it = 0; it < NIT; it++) {
    const bool st = (it < NIT - 1);  // last iter: no new stages
    const int t1 = 2 * it + 1, t2 = 2 * it + 2, t3 = 2 * it + 3;

    // ---- K-tile even (buf0) ----
    ldA(0, 0, 0); ldB(bf0, 0, 0);
    stageA(1, 0, t1); stageA(1, 1, t1);
    sync_mfma(); mm(0, bf0); endp();
    ldA(0, 0, 1); ldB(bf1, 0, 1);
    stageA(1, 2, t1); stageA(1, 3, t1);
    sync_mfma(); mm(0, bf1); endp();
    ldA(0, 1, 0);
    if (st) { stageB(0, 0, t2); stageB(0, 1, t2); }
    sync_mfma(); mm(4, bf0); endp();
    ldA(0, 1, 1);
    if (st) { stageB(0, 2, t2); stageB(0, 3, t2); }
    if (st) asm volatile("s_waitcnt vmcnt(4)" ::: "memory");
    else    asm volatile("s_waitcnt vmcnt(0)" ::: "memory");
    sync_mfma(); mm(4, bf1); endp();

    // ---- K-tile odd (buf1) ----
    ldA(1, 0, 0); ldB(bf0, 1, 0);
    if (st) { stageA(0, 0, t2); stageA(0, 1, t2); }
    sync_mfma(); mm(0, bf0); endp();
    ldA(1, 0, 1); ldB(bf1, 1, 1);
    if (st) { stageA(0, 2, t2); stageA(0, 3, t2); }
    sync_mfma(); mm(0, bf1); endp();
    ldA(1, 1, 0);
    if (st) { stageB(1, 0, t3); stageB(1, 1, t3); }
    sync_mfma(); mm(4, bf0); endp();
    ldA(1, 1, 1);
    if (st) { stageB(1, 2, t3); stageB(1, 3, t3); }
    if (st) asm volatile("s_waitcnt vmcnt(4)" ::: "memory");
    sync_mfma(); mm(4, bf1); endp();
  }

  // ---------------- epilogue ----------------
  if (col0 >= 2048) {                // V: PV-fragment-major scatter into vA
    const int b  = row0 >> 11;
    const int hh = ((col0 - 2048) >> 6) + wn4;
    #pragma unroll
    for (int ktl = 0; ktl < 2; ktl++) {
      const int kt = ((row0 & 2047) >> 6) + wm2 * 2 + ktl;
      short* vbase = vA + ((size_t)((b * 16 + hh) * 32 + kt) * 8) * 512;
      #pragma unroll
      for (int j = 0; j < 4; j++) {
        const float bv = bias[col0 + wn4 * 64 + j * 16 + l16];
        #pragma unroll
        for (int kwp = 0; kwp < 2; kwp++) {
          short8v s8;
          #pragma unroll
          for (int kw = 0; kw < 2; kw++) {
            const int mi = ktl * 4 + kwp * 2 + kw;
            short4v q4 = pack_bf16x4(acc[mi][j][0] + bv, acc[mi][j][1] + bv,
                                     acc[mi][j][2] + bv, acc[mi][j][3] + bv);
            #pragma unroll
            for (int r = 0; r < 4; r++) s8[kw * 4 + r] = q4[r];
          }
          *(short8v*)(vbase + ((size_t)(kwp * 4 + j) * 64 + lane) * 8) = s8;
        }
      }
    }
    return;
  }
  #pragma unroll
  for (int j = 0; j < 4; j++) {      // Q (scaled) / K
    const int col = col0 + wn4 * 64 + j * 16 + l16;
    const float sc = (col < 1024) ? ATT_SCALE : 1.0f;
    const float bv = bias[col];
    #pragma unroll
    for (int mi = 0; mi < 8; mi++) {
      #pragma unroll
      for (int r = 0; r < 4; r++) {
        const int row = row0 + wm2 * 128 + mi * 16 + quad * 4 + r;
        qkv[(size_t)row * 3072 + col] = f2bf((acc[mi][j][r] + bv) * sc);
      }
    }
  }
}

// ---------------- bf16 MFMA GEMM-BT (proj), triple-buffered ----------------
template<int RB, int MODE>
__global__ __launch_bounds__(256) void gemm_bt(
    const short* __restrict__ A, const short* __restrict__ Bt,
    const float* __restrict__ bias, void* __restrict__ Cout,
    short* __restrict__ vA, int M, int N, int K)
{
  __shared__ short As[3][RB][32];
  __shared__ short Bs[3][128][32];
  const int MI = RB / 32;
  const int t    = threadIdx.x;
  const int lane = t & 63;
  const int wave = t >> 6;
  const int wm   = (wave >> 1) * (RB / 2);
  const int wn   = (wave & 1) * 64;
  const int l16  = lane & 15;
  const int quad = lane >> 4;
  const int row0 = blockIdx.y * RB;
  const int col0 = blockIdx.x * 128;

  float4v acc[MI][4] = {};

  const int srow = lane >> 2;
  const int scol = (lane & 3) * 8;
  const int gcol = ((lane & 3) ^ ((srow >> 1) & 3)) * 8;
  const int rquad = (quad ^ ((l16 >> 1) & 3)) * 8;

  const short* gA0 = A + (size_t)(row0 + wave * ((RB == 128) ? 32 : 16) + srow) * K + gcol;
  const short* gA1 = gA0 + (size_t)16 * K;
  const short* gB0 = Bt + (size_t)(col0 + wave * 32 + srow) * K + gcol;
  const short* gB1 = gB0 + (size_t)16 * K;

  const int NI = K / 32;

  auto stage = [&](int kt, int b) {
    const int k0 = kt * 32;
    if (RB == 128) {
      gl_lds16(gA0 + k0, &As[b][wave * 32 + srow][scol]);
      gl_lds16(gA1 + k0, &As[b][wave * 32 + 16 + srow][scol]);
    } else {
      gl_lds16(gA0 + k0, &As[b][(wave * 16 + srow) & (RB - 1)][scol]);
    }
    gl_lds16(gB0 + k0, &Bs[b][wave * 32 + srow][scol]);
    gl_lds16(gB1 + k0, &Bs[b][wave * 32 + 16 + srow][scol]);
  };

  stage(0, 0);
  stage(1, 1);
  if (RB == 128) asm volatile("s_waitcnt vmcnt(4)" ::: "memory");
  else           asm volatile("s_waitcnt vmcnt(3)" ::: "memory");
  __builtin_amdgcn_s_barrier();
  __builtin_amdgcn_sched_barrier(0);

  int buf = 0;
  for (int i = 0; i < NI; i++) {
    if (i + 2 < NI) stage(i + 2, (buf + 2 >= 3) ? buf - 1 : buf + 2);

    short8v af[MI], bf[4];
    #pragma unroll
    for (int ii = 0; ii < MI; ii++)
      af[ii] = *(const short8v*)&As[buf][wm + ii * 16 + l16][rquad];
    #pragma unroll
    for (int j = 0; j < 4; j++)
      bf[j] = *(const short8v*)&Bs[buf][wn + j * 16 + l16][rquad];
    #pragma unroll
    for (int ii = 0; ii < MI; ii++)
      #pragma unroll
      for (int j = 0; j < 4; j++)
        acc[ii][j] = __builtin_amdgcn_mfma_f32_16x16x32_bf16(af[ii], bf[j], acc[ii][j], 0, 0, 0);

    if (i + 1 < NI) {
      if (i + 2 < NI) {
        if (RB == 128) asm volatile("s_waitcnt vmcnt(4)" ::: "memory");
        else           asm volatile("s_waitcnt vmcnt(3)" ::: "memory");
      } else {
        asm volatile("s_waitcnt vmcnt(0)" ::: "memory");
      }
      __builtin_amdgcn_s_barrier();
      __builtin_amdgcn_sched_barrier(0);
    }
    buf = (buf >= 2) ? 0 : buf + 1;
  }

  #pragma unroll
  for (int j = 0; j < 4; j++) {
    const int col = col0 + wn + j * 16 + l16;
    const float bv = bias[col];
    #pragma unroll
    for (int i = 0; i < MI; i++) {
      #pragma unroll
      for (int r = 0; r < 4; r++) {
        const int row = row0 + wm + i * 16 + quad * 4 + r;
        ((float*)Cout)[(size_t)row * N + col] = acc[i][j][r] + bv;
      }
    }
  }
}

// ---------------- MFMA causal flash attention, barrier-free ----------------
// Grid (bh = x, slot = y heavy-first). 4 waves; wave w owns q rows
// [w*16, w*16+16). NO LDS, NO __syncthreads: each wave loads its 8 K-frags
// and 8 V-frags direct from global (L2-resident), fully independent streams.
__global__ __launch_bounds__(256, 4) void attn_mfma(
    const short* __restrict__ qkv, const short* __restrict__ vA,
    short* __restrict__ P0, short* __restrict__ P1, float* __restrict__ lp)
{
  const int bh = blockIdx.x;
  const int b = bh >> 4, h = bh & 15;
  const int s = 79 - blockIdx.y;     // global heavy-first (LPT) order
  int qt = 0, sbase = 0;             // decode slot -> (qt, c); scalar loop
  for (;;) { const int nc = (qt >> 3) + 1; if (s < sbase + nc) break; sbase += nc; qt++; }
  const int c = s - sbase;
  const int kt0  = c * 8;
  const int kend = min(qt + 1, kt0 + 8);

  const int t = threadIdx.x;
  const int lane = t & 63, w = t >> 6;
  const int l16 = lane & 15, quad = lane >> 4;

  const size_t base = (size_t)b * 2048 * 3072;
  const int qoff = h * 64, koff = 1024 + h * 64;
  const int qg = qt * 64 + w * 16 + l16;

  // Q B-frags straight from global (Q pre-scaled in gemm epilogue)
  short8v qf[2];
  #pragma unroll
  for (int ks = 0; ks < 2; ks++)
    qf[ks] = *(const short8v*)(qkv + base + (size_t)qg * 3072 + qoff + ks * 32 + quad * 8);

  float4v O[4] = {};
  float l = 0.0f;

  // K frag base: frag(ks,jm) at tile kt lives at
  //   kg + (kt*64 + jm*16)*3072 + ks*32   (per-lane l16 row, quad col)
  const short* kg = qkv + base + (size_t)l16 * 3072 + koff + quad * 8;
  const short* vg = vA + (size_t)(bh * 32) * 4096 + lane * 8;

  for (int kt = kt0; kt < kend; kt++) {
    // K frags first (QK waits per-MFMA via counted vmcnt), then V frags
    // (PV's waits leave nothing older outstanding that matters).
    short8v kf[8];
    #pragma unroll
    for (int id = 0; id < 8; id++)
      kf[id] = *(const short8v*)(kg + ((size_t)kt * 64 + (id & 3) * 16) * 3072
                                    + (id >> 2) * 32);
    short8v vv[8];
    #pragma unroll
    for (int id = 0; id < 8; id++)
      vv[id] = *(const short8v*)(vg + (size_t)kt * 4096 + id * 512);

    // S^T = K * Q^T
    float4v sv[4] = {};
    __builtin_amdgcn_s_setprio(1);
    #pragma unroll
    for (int ks = 0; ks < 2; ks++)
      #pragma unroll
      for (int jm = 0; jm < 4; jm++)
        sv[jm] = __builtin_amdgcn_mfma_f32_16x16x32_bf16(kf[ks * 4 + jm], qf[ks],
                                                         sv[jm], 0, 0, 0);
    __builtin_amdgcn_s_setprio(0);

    if (kt == qt) {                  // diagonal tile: causal mask
      #pragma unroll
      for (int jm = 0; jm < 4; jm++) {
        const int kv = kt * 64 + jm * 16 + quad * 4;
        #pragma unroll
        for (int r = 0; r < 4; r++)
          if (kv + r > qg) sv[jm][r] = -INFINITY;
      }
    }

    // softmax without running max: p = exp2(s), l += p (no shuffles here)
    short4v pk[4];
    #pragma unroll
    for (int jm = 0; jm < 4; jm++) {
      float p0 = __builtin_amdgcn_exp2f(sv[jm][0]);
      float p1 = __builtin_amdgcn_exp2f(sv[jm][1]);
      float p2 = __builtin_amdgcn_exp2f(sv[jm][2]);
      float p3 = __builtin_amdgcn_exp2f(sv[jm][3]);
      l += (p0 + p1) + (p2 + p3);
      pk[jm] = cvt_pk_bf16x4(p0, p1, p2, p3);
    }

    // O^T += V^T * P^T (V from registers)
    __builtin_amdgcn_s_setprio(1);
    #pragma unroll
    for (int id = 0; id < 8; id++) {
      const int kwp = id >> 2, dm = id & 3;
      const short8v v8 = vv[id];
      const short4v v0 = {v8[0], v8[1], v8[2], v8[3]};
      const short4v v1 = {v8[4], v8[5], v8[6], v8[7]};
      O[dm] = __builtin_amdgcn_mfma_f32_16x16x16bf16_1k(v0, pk[kwp * 2],     O[dm], 0, 0, 0);
      O[dm] = __builtin_amdgcn_mfma_f32_16x16x16bf16_1k(v1, pk[kwp * 2 + 1], O[dm], 0, 0, 0);
    }
    __builtin_amdgcn_s_setprio(0);
  }

  // epilogue: reduce l over the quad group; write UNNORMALIZED bf16 partial
  l += __shfl_xor(l, 16);
  l += __shfl_xor(l, 32);
  const int i = bh * 80 + s;
  short* pp = (i < 2048) ? (P0 + (size_t)i * 4096) : (P1 + (size_t)(i - 2048) * 4096);
  const int row = w * 16 + l16;
  if (quad == 0) lp[(size_t)i * 64 + row] = l;
  short* pr = pp + row * 64;
  #pragma unroll
  for (int dm = 0; dm < 4; dm++)
    *(short4v*)(pr + dm * 16 + quad * 4) =
        pack_bf16x4(O[dm][0], O[dm][1], O[dm][2], O[dm][3]);
}

// ---------------- merge split-K partials -> normalized bf16 aout ------------
__global__ __launch_bounds__(256) void merge_attn(
    const short* __restrict__ P0, const short* __restrict__ P1,
    const float* __restrict__ lp, short* __restrict__ aout)
{
  const int idx = blockIdx.x * 256 + threadIdx.x;   // 524288
  const int q = idx >> 7;
  const int rest = idx & 127;
  const int h  = rest >> 3;
  const int dg = (rest & 7) * 8;
  const int b  = q >> 11;
  const int qr = q & 2047;
  const int qt = qr >> 6;
  const int row = qr & 63;
  const int a = qt >> 3, bq = qt & 7;
  const int off = qt + 4 * a * (a - 1) + a * bq;
  const int nc  = a + 1;
  const int bh  = b * 16 + h;

  float acc[8] = {};
  float suml = 0.0f;
  for (int c = 0; c < nc; c++) {
    const int i = bh * 80 + off + c;
    const short* pp = (i < 2048) ? (P0 + (size_t)i * 4096) : (P1 + (size_t)(i - 2048) * 4096);
    const short8v o = *(const short8v*)(pp + row * 64 + dg);
    #pragma unroll
    for (int k = 0; k < 8; k++) acc[k] += bf2f(o[k]);
    suml += lp[(size_t)i * 64 + row];
  }
  const float inv = 1.0f / suml;
  short8v ov;
  #pragma unroll
  for (int k = 0; k < 8; k++) ov[k] = f2bf(acc[k] * inv);
  *(short8v*)(aout + (size_t)q * 1024 + h * 64 + dg) = ov;
}

extern "C" void kernel_launch(void* const* d_in, const int* in_sizes, int n_in,
                              void* d_out, int out_size, void* d_ws, size_t ws_size,
                              hipStream_t stream) {
  const float* hidden = (const float*)d_in[0];
  const float* w_attn = (const float*)d_in[1];
  const float* b_attn = (const float*)d_in[2];
  const float* w_proj = (const float*)d_in[3];
  const float* b_proj = (const float*)d_in[4];
  float* outp = (float*)d_out;

  char* ws = (char*)d_ws;
  short* hA     = (short*)(ws);                       // then attn P1 overflow
  float* lp     = (float*)(ws + 8ull  * 1024 * 1024); // 655 KB (ex-wqkvT space)
  short* wqkvT  = (short*)(ws + 8ull  * 1024 * 1024);
  short* wprojT = (short*)(ws + 14ull * 1024 * 1024);
  short* qkvb   = (short*)(ws + 16ull * 1024 * 1024);
  short* vAbuf  = (short*)(ws + 40ull * 1024 * 1024); // V frags, then aout
  short* aout   = (short*)(ws + 40ull * 1024 * 1024);
  short* P0     = (short*)d_out;                      // 16 MB partial region

  prep_kernel<<<8192, 256, 0, stream>>>(hidden, w_attn, w_proj, hA, wqkvT, wprojT);
  gemm_qkv256<<<dim3(12, 16), 512, 0, stream>>>(hA, wqkvT, b_attn, qkvb, vAbuf);
  attn_mfma<<<dim3(32, 80), 256, 0, stream>>>(qkvb, vAbuf, P0, hA, lp);
  merge_attn<<<2048, 256, 0, stream>>>(P0, hA, lp, aout);
  gemm_bt<64, 0><<<dim3(8, 64), 256, 0, stream>>>(aout, wprojT, b_proj, outp, nullptr, 4096, 1024, 1024);
}

// Round 8
// 192.175 us; speedup vs baseline: 1.2222x; 1.2222x over previous
//
#include <hip/hip_runtime.h>
#include <hip/hip_bf16.h>

// GPT2 attention: hidden[2,2048,1024] -> qkv gemm -> causal MFMA flash attn
// (single-tile split-K chunks + merge) -> proj
// ws layout (48 MB):
//   hA     bf16 8 MB @ 0      (gemm_qkv A input; dead after -> attn partial
//                              overflow region P1, 4 MB used)
//   wqkvT  bf16 6 MB @ 8 MB   (dead after gemm_qkv -> lp partials, 655 KB)
//   wprojT bf16 2 MB @ 14 MB
//   qkv    bf16 24 MB @ 16 MB (Q scaled by log2(e)/8)
//   vA     bf16 8 MB @ 40 MB  (V in PV-frag layout from gemm epilogue; dead
//                              after attn -> merge writes aout here)
// d_out (16 MB): attn partial region P0 (slots 0..2047), later proj output.
//
// qkv GEMM: 8-phase 256x256 schedule (m201 template), BK=64, 8 waves,
// counted vmcnt(4) at phases 4/8, T2 XOR swizzle via pre-swizzled source.
// proj GEMM: triple-buffered 2-phase structure.
// Attention v7 = round-6 structure + PAIRED K-tiles (2 tiles per barrier):
//   - K via LDS (R7 lesson: direct-per-wave K quadruples VMEM requests on the
//     scatter-shaped K stream -- 2x regression; LDS staging amortizes it).
//   - one __syncthreads per PAIR: prefetch of the next pair gets a full
//     2-tile compute window (~550 cyc) of latency cover vs ~250 before, and
//     barrier count halves. LDS 2 pairs x 2 tiles x 8KB = 32KB.
//   - V direct-from-global per tile (R4-proven), (256,4), LPT grid.

typedef __attribute__((ext_vector_type(4))) float  float4v;
typedef __attribute__((ext_vector_type(8))) short  short8v;
typedef __attribute__((ext_vector_type(4))) short  short4v;

#define ATT_SCALE 0.18033688011112042f   // log2(e) / sqrt(64)

__device__ __forceinline__ short f2bf(float f) {
  union { float f; unsigned u; } v; v.f = f;
  unsigned r = v.u + 0x7fffu + ((v.u >> 16) & 1u);   // RNE
  return (short)(r >> 16);
}
__device__ __forceinline__ float bf2f(short s) {
  union { unsigned u; float f; } v; v.u = ((unsigned)(unsigned short)s) << 16;
  return v.f;
}

// pack 4 floats -> 4 bf16 (round-half-up) via v_perm_b32
__device__ __forceinline__ short4v pack_bf16x4(float a, float b, float c, float d) {
  unsigned x0 = __builtin_bit_cast(unsigned, a) + 0x8000u;
  unsigned x1 = __builtin_bit_cast(unsigned, b) + 0x8000u;
  unsigned x2 = __builtin_bit_cast(unsigned, c) + 0x8000u;
  unsigned x3 = __builtin_bit_cast(unsigned, d) + 0x8000u;
  union { unsigned u[2]; short4v s; } r;
  r.u[0] = __builtin_amdgcn_perm(x1, x0, 0x07060302);
  r.u[1] = __builtin_amdgcn_perm(x3, x2, 0x07060302);
  return r.s;
}

// pack 4 floats -> 4 bf16 (RNE) via v_cvt_pk_bf16_f32
__device__ __forceinline__ short4v cvt_pk_bf16x4(float a, float b, float c, float d) {
  union { unsigned u[2]; short4v s; } r;
  asm("v_cvt_pk_bf16_f32 %0, %1, %2" : "=v"(r.u[0]) : "v"(a), "v"(b));
  asm("v_cvt_pk_bf16_f32 %0, %1, %2" : "=v"(r.u[1]) : "v"(c), "v"(d));
  return r.s;
}

// async global->LDS, 16B per lane; LDS dest = wave-uniform base + lane*16
__device__ __forceinline__ void gl_lds16(const void* g, void* l) {
  __builtin_amdgcn_global_load_lds(
      (const __attribute__((address_space(1))) unsigned*)g,
      (__attribute__((address_space(3))) unsigned*)l, 16, 0, 0);
}

// ---------------- merged prep: hidden->bf16, both weight transposes ----------
__global__ __launch_bounds__(256) void prep_kernel(
    const float* __restrict__ hidden, const float* __restrict__ w_attn,
    const float* __restrict__ w_proj, short* __restrict__ hA,
    short* __restrict__ wqkvT, short* __restrict__ wprojT) {
  __shared__ float tile[32][33];
  const int bx = blockIdx.x, t = threadIdx.x;
  if (bx < 4096) {                     // hidden [4096,1024] fp32 -> bf16
    const size_t i = ((size_t)bx * 256 + t) * 4;
    float4v v = *(const float4v*)(hidden + i);
    short4v o;
    #pragma unroll
    for (int k = 0; k < 4; k++) o[k] = f2bf(v[k]);
    *(short4v*)(hA + i) = o;
    return;
  }
  const float* in; short* out; int R, C, cx, cy;
  if (bx < 4096 + 3072) {              // w_attn [1024,3072] -> [3072,1024]
    in = w_attn; out = wqkvT; R = 1024; C = 3072;
    cx = (bx - 4096) % 96; cy = (bx - 4096) / 96;
  } else {                             // w_proj [1024,1024] -> [1024,1024]
    in = w_proj; out = wprojT; R = 1024; C = 1024;
    cx = (bx - 7168) % 32; cy = (bx - 7168) / 32;
  }
  const int tx = t & 31, ty = t >> 5;  // 32 x 8
  const int c0 = cx * 32, r0 = cy * 32;
  #pragma unroll
  for (int i = 0; i < 4; i++)
    tile[ty + i * 8][tx] = in[(size_t)(r0 + ty + i * 8) * C + c0 + tx];
  __syncthreads();
  #pragma unroll
  for (int i = 0; i < 4; i++) {
    const int cc = ty + i * 8;
    out[(size_t)(c0 + cc) * R + r0 + tx] = f2bf(tile[tx][cc]);
  }
}

// ---------------- qkv GEMM: 8-phase 256x256, BK=64, 8 waves ----------------
__global__ __launch_bounds__(512, 2) void gemm_qkv256(
    const short* __restrict__ A, const short* __restrict__ Bt,
    const float* __restrict__ bias, short* __restrict__ qkv,
    short* __restrict__ vA)
{
  __shared__ short As[2][256][64];   // 64 KB
  __shared__ short Bs[2][256][64];   // 64 KB
  const int K = 1024;
  const int t = threadIdx.x;
  const int lane = t & 63, w = t >> 6;          // 8 waves
  const int wm2 = w >> 2, wn4 = w & 3;          // 2M x 4N wave grid
  const int l16 = lane & 15, quad = lane >> 4;
  const int e7 = l16 & 7;                       // read-side swizzle key
  const int row0 = blockIdx.y * 256;
  const int col0 = blockIdx.x * 256;

  float4v acc[8][4] = {};

  const int srow = w * 8 + (lane >> 3);
  const int slog = (lane & 7) ^ (lane >> 3);
  const short* gA = A + (size_t)(row0 + srow) * K + slog * 8;
  const short* gB = Bt + (size_t)(col0 + srow) * K + slog * 8;
  const int sdst = (lane & 7) * 8;              // within-row shorts

  auto stageA = [&](int b, int qd, int kt) {
    gl_lds16(gA + (size_t)qd * 64 * K + kt * 64,
             &As[b][qd * 64 + w * 8 + (lane >> 3)][sdst]);
  };
  auto stageB = [&](int b, int qd, int kt) {
    gl_lds16(gB + (size_t)qd * 64 * K + kt * 64,
             &Bs[b][qd * 64 + w * 8 + (lane >> 3)][sdst]);
  };

  short8v af[4], bf0[4], bf1[4];
  auto ldA = [&](int b, int mh, int ks) {
    #pragma unroll
    for (int m = 0; m < 4; m++) {
      const int row = wm2 * 128 + mh * 64 + m * 16 + l16;
      af[m] = *(const short8v*)&As[b][row][((ks * 4 + quad) ^ e7) * 8];
    }
  };
  auto ldB = [&](short8v* bf, int b, int ks) {
    #pragma unroll
    for (int n = 0; n < 4; n++) {
      const int row = wn4 * 64 + n * 16 + l16;
      bf[n] = *(const short8v*)&Bs[b][row][((ks * 4 + quad) ^ e7) * 8];
    }
  };
  auto mm = [&](int mb, short8v* bf) {
    __builtin_amdgcn_s_setprio(1);
    #pragma unroll
    for (int m = 0; m < 4; m++)
      #pragma unroll
      for (int n = 0; n < 4; n++)
        acc[mb + m][n] =
            __builtin_amdgcn_mfma_f32_16x16x32_bf16(af[m], bf[n], acc[mb + m][n], 0, 0, 0);
    __builtin_amdgcn_s_setprio(0);
  };
  auto sync_mfma = [&]() {           // barrier -> lgkm drain (rule #18 fence)
    __builtin_amdgcn_sched_barrier(0);
    __builtin_amdgcn_s_barrier();
    asm volatile("s_waitcnt lgkmcnt(0)" ::: "memory");
    __builtin_amdgcn_sched_barrier(0);
  };
  auto endp = [&]() {                // trailing phase barrier
    __builtin_amdgcn_sched_barrier(0);
    __builtin_amdgcn_s_barrier();
    __builtin_amdgcn_sched_barrier(0);
  };

  // prologue: tile 0 (A+B, 8 quarters) + tile 1 B (4 quarters)
  #pragma unroll
  for (int qd = 0; qd < 4; qd++) stageA(0, qd, 0);
  #pragma unroll
  for (int qd = 0; qd < 4; qd++) stageB(0, qd, 0);
  #pragma unroll
  for (int qd = 0; qd < 4; qd++) stageB(1, qd, 1);
  asm volatile("s_waitcnt vmcnt(4)" ::: "memory");   // tile 0 landed
  __builtin_amdgcn_s_barrier();
  __builtin_amdgcn_sched_barrier(0);

  const int NIT = K / 128;           // 8 iterations, 2 K-tiles each
  #pragma unroll 1
  for (int it = 0; it < NIT; it++) {
    const bool st = (it < NIT - 1);  // last iter: no new stages
    const int t1 = 2 * it + 1, t2 = 2 * it + 2, t3 = 2 * it + 3;

    // ---- K-tile even (buf0) ----
    ldA(0, 0, 0); ldB(bf0, 0, 0);
    stageA(1, 0, t1); stageA(1, 1, t1);
    sync_mfma(); mm(0, bf0); endp();
    ldA(0, 0, 1); ldB(bf1, 0, 1);
    stageA(1, 2, t1); stageA(1, 3, t1);
    sync_mfma(); mm(0, bf1); endp();
    ldA(0, 1, 0);
    if (st) { stageB(0, 0, t2); stageB(0, 1, t2); }
    sync_mfma(); mm(4, bf0); endp();
    ldA(0, 1, 1);
    if (st) { stageB(0, 2, t2); stageB(0, 3, t2); }
    if (st) asm volatile("s_waitcnt vmcnt(4)" ::: "memory");
    else    asm volatile("s_waitcnt vmcnt(0)" ::: "memory");
    sync_mfma(); mm(4, bf1); endp();

    // ---- K-tile odd (buf1) ----
    ldA(1, 0, 0); ldB(bf0, 1, 0);
    if (st) { stageA(0, 0, t2); stageA(0, 1, t2); }
    sync_mfma(); mm(0, bf0); endp();
    ldA(1, 0, 1); ldB(bf1, 1, 1);
    if (st) { stageA(0, 2, t2); stageA(0, 3, t2); }
    sync_mfma(); mm(0, bf1); endp();
    ldA(1, 1, 0);
    if (st) { stageB(1, 0, t3); stageB(1, 1, t3); }
    sync_mfma(); mm(4, bf0); endp();
    ldA(1, 1, 1);
    if (st) { stageB(1, 2, t3); stageB(1, 3, t3); }
    if (st) asm volatile("s_waitcnt vmcnt(4)" ::: "memory");
    sync_mfma(); mm(4, bf1); endp();
  }

  // ---------------- epilogue ----------------
  if (col0 >= 2048) {                // V: PV-fragment-major scatter into vA
    const int b  = row0 >> 11;
    const int hh = ((col0 - 2048) >> 6) + wn4;
    #pragma unroll
    for (int ktl = 0; ktl < 2; ktl++) {
      const int kt = ((row0 & 2047) >> 6) + wm2 * 2 + ktl;
      short* vbase = vA + ((size_t)((b * 16 + hh) * 32 + kt) * 8) * 512;
      #pragma unroll
      for (int j = 0; j < 4; j++) {
        const float bv = bias[col0 + wn4 * 64 + j * 16 + l16];
        #pragma unroll
        for (int kwp = 0; kwp < 2; kwp++) {
          short8v s8;
          #pragma unroll
          for (int kw = 0; kw < 2; kw++) {
            const int mi = ktl * 4 + kwp * 2 + kw;
            short4v q4 = pack_bf16x4(acc[mi][j][0] + bv, acc[mi][j][1] + bv,
                                     acc[mi][j][2] + bv, acc[mi][j][3] + bv);
            #pragma unroll
            for (int r = 0; r < 4; r++) s8[kw * 4 + r] = q4[r];
          }
          *(short8v*)(vbase + ((size_t)(kwp * 4 + j) * 64 + lane) * 8) = s8;
        }
      }
    }
    return;
  }
  #pragma unroll
  for (int j = 0; j < 4; j++) {      // Q (scaled) / K
    const int col = col0 + wn4 * 64 + j * 16 + l16;
    const float sc = (col < 1024) ? ATT_SCALE : 1.0f;
    const float bv = bias[col];
    #pragma unroll
    for (int mi = 0; mi < 8; mi++) {
      #pragma unroll
      for (int r = 0; r < 4; r++) {
        const int row = row0 + wm2 * 128 + mi * 16 + quad * 4 + r;
        qkv[(size_t)row * 3072 + col] = f2bf((acc[mi][j][r] + bv) * sc);
      }
    }
  }
}

// ---------------- bf16 MFMA GEMM-BT (proj), triple-buffered ----------------
template<int RB, int MODE>
__global__ __launch_bounds__(256) void gemm_bt(
    const short* __restrict__ A, const short* __restrict__ Bt,
    const float* __restrict__ bias, void* __restrict__ Cout,
    short* __restrict__ vA, int M, int N, int K)
{
  __shared__ short As[3][RB][32];
  __shared__ short Bs[3][128][32];
  const int MI = RB / 32;
  const int t    = threadIdx.x;
  const int lane = t & 63;
  const int wave = t >> 6;
  const int wm   = (wave >> 1) * (RB / 2);
  const int wn   = (wave & 1) * 64;
  const int l16  = lane & 15;
  const int quad = lane >> 4;
  const int row0 = blockIdx.y * RB;
  const int col0 = blockIdx.x * 128;

  float4v acc[MI][4] = {};

  const int srow = lane >> 2;
  const int scol = (lane & 3) * 8;
  const int gcol = ((lane & 3) ^ ((srow >> 1) & 3)) * 8;
  const int rquad = (quad ^ ((l16 >> 1) & 3)) * 8;

  const short* gA0 = A + (size_t)(row0 + wave * ((RB == 128) ? 32 : 16) + srow) * K + gcol;
  const short* gA1 = gA0 + (size_t)16 * K;
  const short* gB0 = Bt + (size_t)(col0 + wave * 32 + srow) * K + gcol;
  const short* gB1 = gB0 + (size_t)16 * K;

  const int NI = K / 32;

  auto stage = [&](int kt, int b) {
    const int k0 = kt * 32;
    if (RB == 128) {
      gl_lds16(gA0 + k0, &As[b][wave * 32 + srow][scol]);
      gl_lds16(gA1 + k0, &As[b][wave * 32 + 16 + srow][scol]);
    } else {
      gl_lds16(gA0 + k0, &As[b][(wave * 16 + srow) & (RB - 1)][scol]);
    }
    gl_lds16(gB0 + k0, &Bs[b][wave * 32 + srow][scol]);
    gl_lds16(gB1 + k0, &Bs[b][wave * 32 + 16 + srow][scol]);
  };

  stage(0, 0);
  stage(1, 1);
  if (RB == 128) asm volatile("s_waitcnt vmcnt(4)" ::: "memory");
  else           asm volatile("s_waitcnt vmcnt(3)" ::: "memory");
  __builtin_amdgcn_s_barrier();
  __builtin_amdgcn_sched_barrier(0);

  int buf = 0;
  for (int i = 0; i < NI; i++) {
    if (i + 2 < NI) stage(i + 2, (buf + 2 >= 3) ? buf - 1 : buf + 2);

    short8v af[MI], bf[4];
    #pragma unroll
    for (int ii = 0; ii < MI; ii++)
      af[ii] = *(const short8v*)&As[buf][wm + ii * 16 + l16][rquad];
    #pragma unroll
    for (int j = 0; j < 4; j++)
      bf[j] = *(const short8v*)&Bs[buf][wn + j * 16 + l16][rquad];
    #pragma unroll
    for (int ii = 0; ii < MI; ii++)
      #pragma unroll
      for (int j = 0; j < 4; j++)
        acc[ii][j] = __builtin_amdgcn_mfma_f32_16x16x32_bf16(af[ii], bf[j], acc[ii][j], 0, 0, 0);

    if (i + 1 < NI) {
      if (i + 2 < NI) {
        if (RB == 128) asm volatile("s_waitcnt vmcnt(4)" ::: "memory");
        else           asm volatile("s_waitcnt vmcnt(3)" ::: "memory");
      } else {
        asm volatile("s_waitcnt vmcnt(0)" ::: "memory");
      }
      __builtin_amdgcn_s_barrier();
      __builtin_amdgcn_sched_barrier(0);
    }
    buf = (buf >= 2) ? 0 : buf + 1;
  }

  #pragma unroll
  for (int j = 0; j < 4; j++) {
    const int col = col0 + wn + j * 16 + l16;
    const float bv = bias[col];
    #pragma unroll
    for (int i = 0; i < MI; i++) {
      #pragma unroll
      for (int r = 0; r < 4; r++) {
        const int row = row0 + wm + i * 16 + quad * 4 + r;
        ((float*)Cout)[(size_t)row * N + col] = acc[i][j][r] + bv;
      }
    }
  }
}

// ---------------- MFMA causal flash attention, paired K-tiles --------------
// Grid (bh = x, slot = y heavy-first). 4 waves; wave w owns q rows
// [w*16, w*16+16). K via LDS pair-buffer: ONE __syncthreads per 2 k-tiles;
// next pair's staging gets a full 2-tile compute window of latency cover.
// V direct-from-global per tile. launch_bounds(256,4) caps unified regs.
__global__ __launch_bounds__(256, 4) void attn_mfma(
    const short* __restrict__ qkv, const short* __restrict__ vA,
    short* __restrict__ P0, short* __restrict__ P1, float* __restrict__ lp)
{
  __shared__ short KA[2][2][8 * 512];   // [pair-buf][slot][frag] = 32 KB

  const int bh = blockIdx.x;
  const int b = bh >> 4, h = bh & 15;
  const int s = 79 - blockIdx.y;     // global heavy-first (LPT) order
  int qt = 0, sbase = 0;             // decode slot -> (qt, c); scalar loop
  for (;;) { const int nc = (qt >> 3) + 1; if (s < sbase + nc) break; sbase += nc; qt++; }
  const int c = s - sbase;
  const int kt0  = c * 8;
  const int kend = min(qt + 1, kt0 + 8);

  const int t = threadIdx.x;
  const int lane = t & 63, w = t >> 6;
  const int l16 = lane & 15, quad = lane >> 4;

  const size_t base = (size_t)b * 2048 * 3072;
  const int qoff = h * 64, koff = 1024 + h * 64;
  const int qg = qt * 64 + w * 16 + l16;

  short8v qf[2];
  #pragma unroll
  for (int ks = 0; ks < 2; ks++)
    qf[ks] = *(const short8v*)(qkv + base + (size_t)qg * 3072 + qoff + ks * 32 + quad * 8);

  float4v O[4] = {};
  float l = 0.0f;

  const int id0 = w * 2, id1 = id0 + 1;
  const int jm0 = id0 & 3, ks0 = id0 >> 2;
  const int jm1 = id1 & 3, ks1 = id1 >> 2;
  const short* kg0 = qkv + base + (size_t)(jm0 * 16 + l16) * 3072 + koff + ks0 * 32 + quad * 8;
  const short* kg1 = qkv + base + (size_t)(jm1 * 16 + l16) * 3072 + koff + ks1 * 32 + quad * 8;
  const short* vg  = vA + (size_t)(bh * 32) * 4096 + lane * 8;

  // stage K tile kt into KA[pb][slot] (2 gl_lds16 per wave)
  auto stageK = [&](int kt, int pb, int slot) {
    gl_lds16(kg0 + (size_t)kt * 64 * 3072, &KA[pb][slot][id0 * 512 + lane * 8]);
    gl_lds16(kg1 + (size_t)kt * 64 * 3072, &KA[pb][slot][id1 * 512 + lane * 8]);
  };

  // per-tile compute: V direct loads -> QK^T -> mask -> exp -> PV
  auto tile_compute = [&](int pb, int slot, int ktc) {
    short8v vv[8];
    #pragma unroll
    for (int id = 0; id < 8; id++)
      vv[id] = *(const short8v*)(vg + (size_t)ktc * 4096 + id * 512);

    float4v sv[4] = {};
    __builtin_amdgcn_s_setprio(1);
    #pragma unroll
    for (int ks = 0; ks < 2; ks++)
      #pragma unroll
      for (int jm = 0; jm < 4; jm++) {
        const short8v kf = *(const short8v*)&KA[pb][slot][(ks * 4 + jm) * 512 + lane * 8];
        sv[jm] = __builtin_amdgcn_mfma_f32_16x16x32_bf16(kf, qf[ks], sv[jm], 0, 0, 0);
      }
    __builtin_amdgcn_s_setprio(0);

    if (ktc == qt) {                 // diagonal tile: causal mask
      #pragma unroll
      for (int jm = 0; jm < 4; jm++) {
        const int kv = ktc * 64 + jm * 16 + quad * 4;
        #pragma unroll
        for (int r = 0; r < 4; r++)
          if (kv + r > qg) sv[jm][r] = -INFINITY;
      }
    }

    short4v pk[4];
    #pragma unroll
    for (int jm = 0; jm < 4; jm++) {
      float p0 = __builtin_amdgcn_exp2f(sv[jm][0]);
      float p1 = __builtin_amdgcn_exp2f(sv[jm][1]);
      float p2 = __builtin_amdgcn_exp2f(sv[jm][2]);
      float p3 = __builtin_amdgcn_exp2f(sv[jm][3]);
      l += (p0 + p1) + (p2 + p3);
      pk[jm] = cvt_pk_bf16x4(p0, p1, p2, p3);
    }

    __builtin_amdgcn_s_setprio(1);
    #pragma unroll
    for (int id = 0; id < 8; id++) {
      const int kwp = id >> 2, dm = id & 3;
      const short8v v8 = vv[id];
      const short4v v0 = {v8[0], v8[1], v8[2], v8[3]};
      const short4v v1 = {v8[4], v8[5], v8[6], v8[7]};
      O[dm] = __builtin_amdgcn_mfma_f32_16x16x16bf16_1k(v0, pk[kwp * 2],     O[dm], 0, 0, 0);
      O[dm] = __builtin_amdgcn_mfma_f32_16x16x16bf16_1k(v1, pk[kwp * 2 + 1], O[dm], 0, 0, 0);
    }
    __builtin_amdgcn_s_setprio(0);
  };

  // prologue: stage first pair into buffer 0
  stageK(kt0, 0, 0);
  if (kt0 + 1 < kend) stageK(kt0 + 1, 0, 1);

  int kt = kt0;
  for (;;) {
    const int pb = ((kt - kt0) >> 1) & 1;
    __syncthreads();                 // pair (kt, kt+1) staged; other buf free
    if (kt + 2 < kend) {             // prefetch next pair (full-pair cover)
      stageK(kt + 2, pb ^ 1, 0);
      if (kt + 3 < kend) stageK(kt + 3, pb ^ 1, 1);
    }
    tile_compute(pb, 0, kt);
    if (++kt == kend) break;
    tile_compute(pb, 1, kt);
    if (++kt == kend) break;
  }

  // epilogue: reduce l over the quad group; write UNNORMALIZED bf16 partial
  l += __shfl_xor(l, 16);
  l += __shfl_xor(l, 32);
  const int i = bh * 80 + s;
  short* pp = (i < 2048) ? (P0 + (size_t)i * 4096) : (P1 + (size_t)(i - 2048) * 4096);
  const int row = w * 16 + l16;
  if (quad == 0) lp[(size_t)i * 64 + row] = l;
  short* pr = pp + row * 64;
  #pragma unroll
  for (int dm = 0; dm < 4; dm++)
    *(short4v*)(pr + dm * 16 + quad * 4) =
        pack_bf16x4(O[dm][0], O[dm][1], O[dm][2], O[dm][3]);
}

// ---------------- merge split-K partials -> normalized bf16 aout ------------
__global__ __launch_bounds__(256) void merge_attn(
    const short* __restrict__ P0, const short* __restrict__ P1,
    const float* __restrict__ lp, short* __restrict__ aout)
{
  const int idx = blockIdx.x * 256 + threadIdx.x;   // 524288
  const int q = idx >> 7;
  const int rest = idx & 127;
  const int h  = rest >> 3;
  const int dg = (rest & 7) * 8;
  const int b  = q >> 11;
  const int qr = q & 2047;
  const int qt = qr >> 6;
  const int row = qr & 63;
  const int a = qt >> 3, bq = qt & 7;
  const int off = qt + 4 * a * (a - 1) + a * bq;
  const int nc  = a + 1;
  const int bh  = b * 16 + h;

  float acc[8] = {};
  float suml = 0.0f;
  for (int c = 0; c < nc; c++) {
    const int i = bh * 80 + off + c;
    const short* pp = (i < 2048) ? (P0 + (size_t)i * 4096) : (P1 + (size_t)(i - 2048) * 4096);
    const short8v o = *(const short8v*)(pp + row * 64 + dg);
    #pragma unroll
    for (int k = 0; k < 8; k++) acc[k] += bf2f(o[k]);
    suml += lp[(size_t)i * 64 + row];
  }
  const float inv = 1.0f / suml;
  short8v ov;
  #pragma unroll
  for (int k = 0; k < 8; k++) ov[k] = f2bf(acc[k] * inv);
  *(short8v*)(aout + (size_t)q * 1024 + h * 64 + dg) = ov;
}

extern "C" void kernel_launch(void* const* d_in, const int* in_sizes, int n_in,
                              void* d_out, int out_size, void* d_ws, size_t ws_size,
                              hipStream_t stream) {
  const float* hidden = (const float*)d_in[0];
  const float* w_attn = (const float*)d_in[1];
  const float* b_attn = (const float*)d_in[2];
  const float* w_proj = (const float*)d_in[3];
  const float* b_proj = (const float*)d_in[4];
  float* outp = (float*)d_out;

  char* ws = (char*)d_ws;
  short* hA     = (short*)(ws);                       // then attn P1 overflow
  float* lp     = (float*)(ws + 8ull  * 1024 * 1024); // 655 KB (ex-wqkvT space)
  short* wqkvT  = (short*)(ws + 8ull  * 1024 * 1024);
  short* wprojT = (short*)(ws + 14ull * 1024 * 1024);
  short* qkvb   = (short*)(ws + 16ull * 1024 * 1024);
  short* vAbuf  = (short*)(ws + 40ull * 1024 * 1024); // V frags, then aout
  short* aout   = (short*)(ws + 40ull * 1024 * 1024);
  short* P0     = (short*)d_out;                      // 16 MB partial region

  prep_kernel<<<8192, 256, 0, stream>>>(hidden, w_attn, w_proj, hA, wqkvT, wprojT);
  gemm_qkv256<<<dim3(12, 16), 512, 0, stream>>>(hA, wqkvT, b_attn, qkvb, vAbuf);
  attn_mfma<<<dim3(32, 80), 256, 0, stream>>>(qkvb, vAbuf, P0, hA, lp);
  merge_attn<<<2048, 256, 0, stream>>>(P0, hA, lp, aout);
  gemm_bt<64, 0><<<dim3(8, 64), 256, 0, stream>>>(aout, wprojT, b_proj, outp, nullptr, 4096, 1024, 1024);
}

// Round 9
// 184.283 us; speedup vs baseline: 1.2746x; 1.0428x over previous
//
#include <hip/hip_runtime.h>
#include <hip/hip_bf16.h>

// GPT2 attention: hidden[2,2048,1024] -> qkv gemm -> causal MFMA flash attn
// (single-tile split-K chunks + merge) -> proj
// ws layout (48 MB):
//   hA     bf16 8 MB @ 0      (gemm_qkv A input; dead after -> attn partial
//                              overflow region P1, 4 MB used)
//   wqkvT  bf16 6 MB @ 8 MB   (dead after gemm_qkv -> lp partials, 655 KB)
//   wprojT bf16 2 MB @ 14 MB
//   qkv    bf16 24 MB @ 16 MB (Q scaled by log2(e)/8)
//   vA     bf16 8 MB @ 40 MB  (V in PV-frag layout from gemm epilogue; dead
//                              after attn -> merge writes aout here)
// d_out (16 MB): attn partial region P0 (slots 0..2047), later proj output.
//
// qkv GEMM: 8-phase 256x256 schedule (m201 template), BK=64, 8 waves,
// counted vmcnt(4) at phases 4/8, T2 XOR swizzle via pre-swizzled source.
// proj GEMM: triple-buffered 2-phase structure.
// Attention v8: 2 WAVES x 32 Q-ROWS (was 4 waves x 16). Evidence R4-R8: all
// scheduling levers null; wall = ~4000-cyc latency chain per 64-k tile x 66
// chains/SIMD with ~2.5-way overlap. Fix the chain COUNT: each wave carries
// two 16-row Q halves -> MFMA per chain doubles (16 QK + 32 PV), chains
// halve (33/SIMD), V loads per block-tile halve. K stays LDS-shared (R7:
// direct K = 4x request traffic, 2x regression). 128 thr, 16 KB LDS,
// launch_bounds(128,3) -> ~6 blocks/CU = 3 independent streams/SIMD.

typedef __attribute__((ext_vector_type(4))) float  float4v;
typedef __attribute__((ext_vector_type(8))) short  short8v;
typedef __attribute__((ext_vector_type(4))) short  short4v;

#define ATT_SCALE 0.18033688011112042f   // log2(e) / sqrt(64)

__device__ __forceinline__ short f2bf(float f) {
  union { float f; unsigned u; } v; v.f = f;
  unsigned r = v.u + 0x7fffu + ((v.u >> 16) & 1u);   // RNE
  return (short)(r >> 16);
}
__device__ __forceinline__ float bf2f(short s) {
  union { unsigned u; float f; } v; v.u = ((unsigned)(unsigned short)s) << 16;
  return v.f;
}

// pack 4 floats -> 4 bf16 (round-half-up) via v_perm_b32
__device__ __forceinline__ short4v pack_bf16x4(float a, float b, float c, float d) {
  unsigned x0 = __builtin_bit_cast(unsigned, a) + 0x8000u;
  unsigned x1 = __builtin_bit_cast(unsigned, b) + 0x8000u;
  unsigned x2 = __builtin_bit_cast(unsigned, c) + 0x8000u;
  unsigned x3 = __builtin_bit_cast(unsigned, d) + 0x8000u;
  union { unsigned u[2]; short4v s; } r;
  r.u[0] = __builtin_amdgcn_perm(x1, x0, 0x07060302);
  r.u[1] = __builtin_amdgcn_perm(x3, x2, 0x07060302);
  return r.s;
}

// pack 4 floats -> 4 bf16 (RNE) via v_cvt_pk_bf16_f32
__device__ __forceinline__ short4v cvt_pk_bf16x4(float a, float b, float c, float d) {
  union { unsigned u[2]; short4v s; } r;
  asm("v_cvt_pk_bf16_f32 %0, %1, %2" : "=v"(r.u[0]) : "v"(a), "v"(b));
  asm("v_cvt_pk_bf16_f32 %0, %1, %2" : "=v"(r.u[1]) : "v"(c), "v"(d));
  return r.s;
}

// async global->LDS, 16B per lane; LDS dest = wave-uniform base + lane*16
__device__ __forceinline__ void gl_lds16(const void* g, void* l) {
  __builtin_amdgcn_global_load_lds(
      (const __attribute__((address_space(1))) unsigned*)g,
      (__attribute__((address_space(3))) unsigned*)l, 16, 0, 0);
}

// ---------------- merged prep: hidden->bf16, both weight transposes ----------
__global__ __launch_bounds__(256) void prep_kernel(
    const float* __restrict__ hidden, const float* __restrict__ w_attn,
    const float* __restrict__ w_proj, short* __restrict__ hA,
    short* __restrict__ wqkvT, short* __restrict__ wprojT) {
  __shared__ float tile[32][33];
  const int bx = blockIdx.x, t = threadIdx.x;
  if (bx < 4096) {                     // hidden [4096,1024] fp32 -> bf16
    const size_t i = ((size_t)bx * 256 + t) * 4;
    float4v v = *(const float4v*)(hidden + i);
    short4v o;
    #pragma unroll
    for (int k = 0; k < 4; k++) o[k] = f2bf(v[k]);
    *(short4v*)(hA + i) = o;
    return;
  }
  const float* in; short* out; int R, C, cx, cy;
  if (bx < 4096 + 3072) {              // w_attn [1024,3072] -> [3072,1024]
    in = w_attn; out = wqkvT; R = 1024; C = 3072;
    cx = (bx - 4096) % 96; cy = (bx - 4096) / 96;
  } else {                             // w_proj [1024,1024] -> [1024,1024]
    in = w_proj; out = wprojT; R = 1024; C = 1024;
    cx = (bx - 7168) % 32; cy = (bx - 7168) / 32;
  }
  const int tx = t & 31, ty = t >> 5;  // 32 x 8
  const int c0 = cx * 32, r0 = cy * 32;
  #pragma unroll
  for (int i = 0; i < 4; i++)
    tile[ty + i * 8][tx] = in[(size_t)(r0 + ty + i * 8) * C + c0 + tx];
  __syncthreads();
  #pragma unroll
  for (int i = 0; i < 4; i++) {
    const int cc = ty + i * 8;
    out[(size_t)(c0 + cc) * R + r0 + tx] = f2bf(tile[tx][cc]);
  }
}

// ---------------- qkv GEMM: 8-phase 256x256, BK=64, 8 waves ----------------
__global__ __launch_bounds__(512, 2) void gemm_qkv256(
    const short* __restrict__ A, const short* __restrict__ Bt,
    const float* __restrict__ bias, short* __restrict__ qkv,
    short* __restrict__ vA)
{
  __shared__ short As[2][256][64];   // 64 KB
  __shared__ short Bs[2][256][64];   // 64 KB
  const int K = 1024;
  const int t = threadIdx.x;
  const int lane = t & 63, w = t >> 6;          // 8 waves
  const int wm2 = w >> 2, wn4 = w & 3;          // 2M x 4N wave grid
  const int l16 = lane & 15, quad = lane >> 4;
  const int e7 = l16 & 7;                       // read-side swizzle key
  const int row0 = blockIdx.y * 256;
  const int col0 = blockIdx.x * 256;

  float4v acc[8][4] = {};

  const int srow = w * 8 + (lane >> 3);
  const int slog = (lane & 7) ^ (lane >> 3);
  const short* gA = A + (size_t)(row0 + srow) * K + slog * 8;
  const short* gB = Bt + (size_t)(col0 + srow) * K + slog * 8;
  const int sdst = (lane & 7) * 8;              // within-row shorts

  auto stageA = [&](int b, int qd, int kt) {
    gl_lds16(gA + (size_t)qd * 64 * K + kt * 64,
             &As[b][qd * 64 + w * 8 + (lane >> 3)][sdst]);
  };
  auto stageB = [&](int b, int qd, int kt) {
    gl_lds16(gB + (size_t)qd * 64 * K + kt * 64,
             &Bs[b][qd * 64 + w * 8 + (lane >> 3)][sdst]);
  };

  short8v af[4], bf0[4], bf1[4];
  auto ldA = [&](int b, int mh, int ks) {
    #pragma unroll
    for (int m = 0; m < 4; m++) {
      const int row = wm2 * 128 + mh * 64 + m * 16 + l16;
      af[m] = *(const short8v*)&As[b][row][((ks * 4 + quad) ^ e7) * 8];
    }
  };
  auto ldB = [&](short8v* bf, int b, int ks) {
    #pragma unroll
    for (int n = 0; n < 4; n++) {
      const int row = wn4 * 64 + n * 16 + l16;
      bf[n] = *(const short8v*)&Bs[b][row][((ks * 4 + quad) ^ e7) * 8];
    }
  };
  auto mm = [&](int mb, short8v* bf) {
    __builtin_amdgcn_s_setprio(1);
    #pragma unroll
    for (int m = 0; m < 4; m++)
      #pragma unroll
      for (int n = 0; n < 4; n++)
        acc[mb + m][n] =
            __builtin_amdgcn_mfma_f32_16x16x32_bf16(af[m], bf[n], acc[mb + m][n], 0, 0, 0);
    __builtin_amdgcn_s_setprio(0);
  };
  auto sync_mfma = [&]() {           // barrier -> lgkm drain (rule #18 fence)
    __builtin_amdgcn_sched_barrier(0);
    __builtin_amdgcn_s_barrier();
    asm volatile("s_waitcnt lgkmcnt(0)" ::: "memory");
    __builtin_amdgcn_sched_barrier(0);
  };
  auto endp = [&]() {                // trailing phase barrier
    __builtin_amdgcn_sched_barrier(0);
    __builtin_amdgcn_s_barrier();
    __builtin_amdgcn_sched_barrier(0);
  };

  // prologue: tile 0 (A+B, 8 quarters) + tile 1 B (4 quarters)
  #pragma unroll
  for (int qd = 0; qd < 4; qd++) stageA(0, qd, 0);
  #pragma unroll
  for (int qd = 0; qd < 4; qd++) stageB(0, qd, 0);
  #pragma unroll
  for (int qd = 0; qd < 4; qd++) stageB(1, qd, 1);
  asm volatile("s_waitcnt vmcnt(4)" ::: "memory");   // tile 0 landed
  __builtin_amdgcn_s_barrier();
  __builtin_amdgcn_sched_barrier(0);

  const int NIT = K / 128;           // 8 iterations, 2 K-tiles each
  #pragma unroll 1
  for (int it = 0; it < NIT; it++) {
    const bool st = (it < NIT - 1);  // last iter: no new stages
    const int t1 = 2 * it + 1, t2 = 2 * it + 2, t3 = 2 * it + 3;

    // ---- K-tile even (buf0) ----
    ldA(0, 0, 0); ldB(bf0, 0, 0);
    stageA(1, 0, t1); stageA(1, 1, t1);
    sync_mfma(); mm(0, bf0); endp();
    ldA(0, 0, 1); ldB(bf1, 0, 1);
    stageA(1, 2, t1); stageA(1, 3, t1);
    sync_mfma(); mm(0, bf1); endp();
    ldA(0, 1, 0);
    if (st) { stageB(0, 0, t2); stageB(0, 1, t2); }
    sync_mfma(); mm(4, bf0); endp();
    ldA(0, 1, 1);
    if (st) { stageB(0, 2, t2); stageB(0, 3, t2); }
    if (st) asm volatile("s_waitcnt vmcnt(4)" ::: "memory");
    else    asm volatile("s_waitcnt vmcnt(0)" ::: "memory");
    sync_mfma(); mm(4, bf1); endp();

    // ---- K-tile odd (buf1) ----
    ldA(1, 0, 0); ldB(bf0, 1, 0);
    if (st) { stageA(0, 0, t2); stageA(0, 1, t2); }
    sync_mfma(); mm(0, bf0); endp();
    ldA(1, 0, 1); ldB(bf1, 1, 1);
    if (st) { stageA(0, 2, t2); stageA(0, 3, t2); }
    sync_mfma(); mm(0, bf1); endp();
    ldA(1, 1, 0);
    if (st) { stageB(1, 0, t3); stageB(1, 1, t3); }
    sync_mfma(); mm(4, bf0); endp();
    ldA(1, 1, 1);
    if (st) { stageB(1, 2, t3); stageB(1, 3, t3); }
    if (st) asm volatile("s_waitcnt vmcnt(4)" ::: "memory");
    sync_mfma(); mm(4, bf1); endp();
  }

  // ---------------- epilogue ----------------
  if (col0 >= 2048) {                // V: PV-fragment-major scatter into vA
    const int b  = row0 >> 11;
    const int hh = ((col0 - 2048) >> 6) + wn4;
    #pragma unroll
    for (int ktl = 0; ktl < 2; ktl++) {
      const int kt = ((row0 & 2047) >> 6) + wm2 * 2 + ktl;
      short* vbase = vA + ((size_t)((b * 16 + hh) * 32 + kt) * 8) * 512;
      #pragma unroll
      for (int j = 0; j < 4; j++) {
        const float bv = bias[col0 + wn4 * 64 + j * 16 + l16];
        #pragma unroll
        for (int kwp = 0; kwp < 2; kwp++) {
          short8v s8;
          #pragma unroll
          for (int kw = 0; kw < 2; kw++) {
            const int mi = ktl * 4 + kwp * 2 + kw;
            short4v q4 = pack_bf16x4(acc[mi][j][0] + bv, acc[mi][j][1] + bv,
                                     acc[mi][j][2] + bv, acc[mi][j][3] + bv);
            #pragma unroll
            for (int r = 0; r < 4; r++) s8[kw * 4 + r] = q4[r];
          }
          *(short8v*)(vbase + ((size_t)(kwp * 4 + j) * 64 + lane) * 8) = s8;
        }
      }
    }
    return;
  }
  #pragma unroll
  for (int j = 0; j < 4; j++) {      // Q (scaled) / K
    const int col = col0 + wn4 * 64 + j * 16 + l16;
    const float sc = (col < 1024) ? ATT_SCALE : 1.0f;
    const float bv = bias[col];
    #pragma unroll
    for (int mi = 0; mi < 8; mi++) {
      #pragma unroll
      for (int r = 0; r < 4; r++) {
        const int row = row0 + wm2 * 128 + mi * 16 + quad * 4 + r;
        qkv[(size_t)row * 3072 + col] = f2bf((acc[mi][j][r] + bv) * sc);
      }
    }
  }
}

// ---------------- bf16 MFMA GEMM-BT (proj), triple-buffered ----------------
template<int RB, int MODE>
__global__ __launch_bounds__(256) void gemm_bt(
    const short* __restrict__ A, const short* __restrict__ Bt,
    const float* __restrict__ bias, void* __restrict__ Cout,
    short* __restrict__ vA, int M, int N, int K)
{
  __shared__ short As[3][RB][32];
  __shared__ short Bs[3][128][32];
  const int MI = RB / 32;
  const int t    = threadIdx.x;
  const int lane = t & 63;
  const int wave = t >> 6;
  const int wm   = (wave >> 1) * (RB / 2);
  const int wn   = (wave & 1) * 64;
  const int l16  = lane & 15;
  const int quad = lane >> 4;
  const int row0 = blockIdx.y * RB;
  const int col0 = blockIdx.x * 128;

  float4v acc[MI][4] = {};

  const int srow = lane >> 2;
  const int scol = (lane & 3) * 8;
  const int gcol = ((lane & 3) ^ ((srow >> 1) & 3)) * 8;
  const int rquad = (quad ^ ((l16 >> 1) & 3)) * 8;

  const short* gA0 = A + (size_t)(row0 + wave * ((RB == 128) ? 32 : 16) + srow) * K + gcol;
  const short* gA1 = gA0 + (size_t)16 * K;
  const short* gB0 = Bt + (size_t)(col0 + wave * 32 + srow) * K + gcol;
  const short* gB1 = gB0 + (size_t)16 * K;

  const int NI = K / 32;

  auto stage = [&](int kt, int b) {
    const int k0 = kt * 32;
    if (RB == 128) {
      gl_lds16(gA0 + k0, &As[b][wave * 32 + srow][scol]);
      gl_lds16(gA1 + k0, &As[b][wave * 32 + 16 + srow][scol]);
    } else {
      gl_lds16(gA0 + k0, &As[b][(wave * 16 + srow) & (RB - 1)][scol]);
    }
    gl_lds16(gB0 + k0, &Bs[b][wave * 32 + srow][scol]);
    gl_lds16(gB1 + k0, &Bs[b][wave * 32 + 16 + srow][scol]);
  };

  stage(0, 0);
  stage(1, 1);
  if (RB == 128) asm volatile("s_waitcnt vmcnt(4)" ::: "memory");
  else           asm volatile("s_waitcnt vmcnt(3)" ::: "memory");
  __builtin_amdgcn_s_barrier();
  __builtin_amdgcn_sched_barrier(0);

  int buf = 0;
  for (int i = 0; i < NI; i++) {
    if (i + 2 < NI) stage(i + 2, (buf + 2 >= 3) ? buf - 1 : buf + 2);

    short8v af[MI], bf[4];
    #pragma unroll
    for (int ii = 0; ii < MI; ii++)
      af[ii] = *(const short8v*)&As[buf][wm + ii * 16 + l16][rquad];
    #pragma unroll
    for (int j = 0; j < 4; j++)
      bf[j] = *(const short8v*)&Bs[buf][wn + j * 16 + l16][rquad];
    #pragma unroll
    for (int ii = 0; ii < MI; ii++)
      #pragma unroll
      for (int j = 0; j < 4; j++)
        acc[ii][j] = __builtin_amdgcn_mfma_f32_16x16x32_bf16(af[ii], bf[j], acc[ii][j], 0, 0, 0);

    if (i + 1 < NI) {
      if (i + 2 < NI) {
        if (RB == 128) asm volatile("s_waitcnt vmcnt(4)" ::: "memory");
        else           asm volatile("s_waitcnt vmcnt(3)" ::: "memory");
      } else {
        asm volatile("s_waitcnt vmcnt(0)" ::: "memory");
      }
      __builtin_amdgcn_s_barrier();
      __builtin_amdgcn_sched_barrier(0);
    }
    buf = (buf >= 2) ? 0 : buf + 1;
  }

  #pragma unroll
  for (int j = 0; j < 4; j++) {
    const int col = col0 + wn + j * 16 + l16;
    const float bv = bias[col];
    #pragma unroll
    for (int i = 0; i < MI; i++) {
      #pragma unroll
      for (int r = 0; r < 4; r++) {
        const int row = row0 + wm + i * 16 + quad * 4 + r;
        ((float*)Cout)[(size_t)row * N + col] = acc[i][j][r] + bv;
      }
    }
  }
}

// ---------------- MFMA causal flash attention, 2 waves x 32 rows -----------
// Grid (bh = x, slot = y heavy-first). 2 waves of 64; wave w owns q rows
// [w*32, w*32+32) as two 16-row halves. K via LDS double-buffer (wave w
// stages frag ids w*4+j, i.e. ks=w, jm=j); V direct-from-global per tile
// (shared by both halves -> arithmetic per load doubled vs v7).
__global__ __launch_bounds__(128, 3) void attn_mfma(
    const short* __restrict__ qkv, const short* __restrict__ vA,
    short* __restrict__ P0, short* __restrict__ P1, float* __restrict__ lp)
{
  __shared__ short KA[2][8 * 512];   // frag-major chunks, id = ks*4+jm (16 KB)

  const int bh = blockIdx.x;
  const int b = bh >> 4, h = bh & 15;
  const int s = 79 - blockIdx.y;     // global heavy-first (LPT) order
  int qt = 0, sbase = 0;             // decode slot -> (qt, c); scalar loop
  for (;;) { const int nc = (qt >> 3) + 1; if (s < sbase + nc) break; sbase += nc; qt++; }
  const int c = s - sbase;
  const int kt0  = c * 8;
  const int kend = min(qt + 1, kt0 + 8);

  const int t = threadIdx.x;
  const int lane = t & 63, w = t >> 6;          // 2 waves
  const int l16 = lane & 15, quad = lane >> 4;

  const size_t base = (size_t)b * 2048 * 3072;
  const int qoff = h * 64, koff = 1024 + h * 64;

  // two 16-row halves per wave: q rows qt*64 + w*32 + hh*16 + l16
  int qg[2];
  short8v qf[2][2];                  // [half][ks]
  #pragma unroll
  for (int hh = 0; hh < 2; hh++) {
    qg[hh] = qt * 64 + w * 32 + hh * 16 + l16;
    #pragma unroll
    for (int ks = 0; ks < 2; ks++)
      qf[hh][ks] = *(const short8v*)(qkv + base + (size_t)qg[hh] * 3072
                                     + qoff + ks * 32 + quad * 8);
  }

  float4v O[2][4] = {};
  float l[2] = {0.0f, 0.0f};

  // wave w stages frag ids w*4+j (ks=w fixed, jm=j):
  // addr = (jm*16 + l16)*3072 + koff + ks*32 + quad*8
  const short* kgw = qkv + base + (size_t)l16 * 3072 + koff + w * 32 + quad * 8;
  const short* vg  = vA + (size_t)(bh * 32) * 4096 + lane * 8;

  auto stageK = [&](int kt, int buf) {
    #pragma unroll
    for (int j = 0; j < 4; j++)
      gl_lds16(kgw + ((size_t)kt * 64 + j * 16) * 3072,
               &KA[buf][(w * 4 + j) * 512 + lane * 8]);
  };

  stageK(kt0, 0);                    // prefetch first K tile

  for (int kt = kt0; kt < kend; kt++) {
    const int buf = (kt - kt0) & 1;
    __syncthreads();                 // K tile kt staged; other buffer free

    // V frags for THIS tile, direct to registers (shared by both halves)
    short8v vv[8];
    #pragma unroll
    for (int id = 0; id < 8; id++)
      vv[id] = *(const short8v*)(vg + (size_t)kt * 4096 + id * 512);

    if (kt + 1 < kend) stageK(kt + 1, buf ^ 1);  // async K prefetch

    // S^T = K * Q^T for both halves (K frag reused across halves)
    float4v sv[2][4] = {};
    __builtin_amdgcn_s_setprio(1);
    #pragma unroll
    for (int ks = 0; ks < 2; ks++)
      #pragma unroll
      for (int jm = 0; jm < 4; jm++) {
        const short8v kf = *(const short8v*)&KA[buf][(ks * 4 + jm) * 512 + lane * 8];
        #pragma unroll
        for (int hh = 0; hh < 2; hh++)
          sv[hh][jm] = __builtin_amdgcn_mfma_f32_16x16x32_bf16(kf, qf[hh][ks],
                                                               sv[hh][jm], 0, 0, 0);
      }
    __builtin_amdgcn_s_setprio(0);

    if (kt == qt) {                  // diagonal tile: causal mask
      #pragma unroll
      for (int hh = 0; hh < 2; hh++)
        #pragma unroll
        for (int jm = 0; jm < 4; jm++) {
          const int kv = kt * 64 + jm * 16 + quad * 4;
          #pragma unroll
          for (int r = 0; r < 4; r++)
            if (kv + r > qg[hh]) sv[hh][jm][r] = -INFINITY;
        }
    }

    // softmax without running max: p = exp2(s), l += p
    short4v pk[2][4];
    #pragma unroll
    for (int hh = 0; hh < 2; hh++)
      #pragma unroll
      for (int jm = 0; jm < 4; jm++) {
        float p0 = __builtin_amdgcn_exp2f(sv[hh][jm][0]);
        float p1 = __builtin_amdgcn_exp2f(sv[hh][jm][1]);
        float p2 = __builtin_amdgcn_exp2f(sv[hh][jm][2]);
        float p3 = __builtin_amdgcn_exp2f(sv[hh][jm][3]);
        l[hh] += (p0 + p1) + (p2 + p3);
        pk[hh][jm] = cvt_pk_bf16x4(p0, p1, p2, p3);
      }

    // O^T += V^T * P^T for both halves (V frag reused across halves)
    __builtin_amdgcn_s_setprio(1);
    #pragma unroll
    for (int id = 0; id < 8; id++) {
      const int kwp = id >> 2, dm = id & 3;
      const short8v v8 = vv[id];
      const short4v v0 = {v8[0], v8[1], v8[2], v8[3]};
      const short4v v1 = {v8[4], v8[5], v8[6], v8[7]};
      #pragma unroll
      for (int hh = 0; hh < 2; hh++) {
        O[hh][dm] = __builtin_amdgcn_mfma_f32_16x16x16bf16_1k(v0, pk[hh][kwp * 2],
                                                              O[hh][dm], 0, 0, 0);
        O[hh][dm] = __builtin_amdgcn_mfma_f32_16x16x16bf16_1k(v1, pk[hh][kwp * 2 + 1],
                                                              O[hh][dm], 0, 0, 0);
      }
    }
    __builtin_amdgcn_s_setprio(0);
  }

  // epilogue: reduce l over the quad group; write UNNORMALIZED bf16 partial
  #pragma unroll
  for (int hh = 0; hh < 2; hh++) {
    l[hh] += __shfl_xor(l[hh], 16);
    l[hh] += __shfl_xor(l[hh], 32);
  }
  const int i = bh * 80 + s;
  short* pp = (i < 2048) ? (P0 + (size_t)i * 4096) : (P1 + (size_t)(i - 2048) * 4096);
  #pragma unroll
  for (int hh = 0; hh < 2; hh++) {
    const int row = w * 32 + hh * 16 + l16;
    if (quad == 0) lp[(size_t)i * 64 + row] = l[hh];
    short* pr = pp + row * 64;
    #pragma unroll
    for (int dm = 0; dm < 4; dm++)
      *(short4v*)(pr + dm * 16 + quad * 4) =
          pack_bf16x4(O[hh][dm][0], O[hh][dm][1], O[hh][dm][2], O[hh][dm][3]);
  }
}

// ---------------- merge split-K partials -> normalized bf16 aout ------------
__global__ __launch_bounds__(256) void merge_attn(
    const short* __restrict__ P0, const short* __restrict__ P1,
    const float* __restrict__ lp, short* __restrict__ aout)
{
  const int idx = blockIdx.x * 256 + threadIdx.x;   // 524288
  const int q = idx >> 7;
  const int rest = idx & 127;
  const int h  = rest >> 3;
  const int dg = (rest & 7) * 8;
  const int b  = q >> 11;
  const int qr = q & 2047;
  const int qt = qr >> 6;
  const int row = qr & 63;
  const int a = qt >> 3, bq = qt & 7;
  const int off = qt + 4 * a * (a - 1) + a * bq;
  const int nc  = a + 1;
  const int bh  = b * 16 + h;

  float acc[8] = {};
  float suml = 0.0f;
  for (int c = 0; c < nc; c++) {
    const int i = bh * 80 + off + c;
    const short* pp = (i < 2048) ? (P0 + (size_t)i * 4096) : (P1 + (size_t)(i - 2048) * 4096);
    const short8v o = *(const short8v*)(pp + row * 64 + dg);
    #pragma unroll
    for (int k = 0; k < 8; k++) acc[k] += bf2f(o[k]);
    suml += lp[(size_t)i * 64 + row];
  }
  const float inv = 1.0f / suml;
  short8v ov;
  #pragma unroll
  for (int k = 0; k < 8; k++) ov[k] = f2bf(acc[k] * inv);
  *(short8v*)(aout + (size_t)q * 1024 + h * 64 + dg) = ov;
}

extern "C" void kernel_launch(void* const* d_in, const int* in_sizes, int n_in,
                              void* d_out, int out_size, void* d_ws, size_t ws_size,
                              hipStream_t stream) {
  const float* hidden = (const float*)d_in[0];
  const float* w_attn = (const float*)d_in[1];
  const float* b_attn = (const float*)d_in[2];
  const float* w_proj = (const float*)d_in[3];
  const float* b_proj = (const float*)d_in[4];
  float* outp = (float*)d_out;

  char* ws = (char*)d_ws;
  short* hA     = (short*)(ws);                       // then attn P1 overflow
  float* lp     = (float*)(ws + 8ull  * 1024 * 1024); // 655 KB (ex-wqkvT space)
  short* wqkvT  = (short*)(ws + 8ull  * 1024 * 1024);
  short* wprojT = (short*)(ws + 14ull * 1024 * 1024);
  short* qkvb   = (short*)(ws + 16ull * 1024 * 1024);
  short* vAbuf  = (short*)(ws + 40ull * 1024 * 1024); // V frags, then aout
  short* aout   = (short*)(ws + 40ull * 1024 * 1024);
  short* P0     = (short*)d_out;                      // 16 MB partial region

  prep_kernel<<<8192, 256, 0, stream>>>(hidden, w_attn, w_proj, hA, wqkvT, wprojT);
  gemm_qkv256<<<dim3(12, 16), 512, 0, stream>>>(hA, wqkvT, b_attn, qkvb, vAbuf);
  attn_mfma<<<dim3(32, 80), 128, 0, stream>>>(qkvb, vAbuf, P0, hA, lp);
  merge_attn<<<2048, 256, 0, stream>>>(P0, hA, lp, aout);
  gemm_bt<64, 0><<<dim3(8, 64), 256, 0, stream>>>(aout, wprojT, b_proj, outp, nullptr, 4096, 1024, 1024);
}